// Round 1
// baseline (26252.499 us; speedup 1.0000x reference)
//
#include <hip/hip_runtime.h>

#define TT 128
#define BB 32
#define II 128
#define HH 320
#define OO 32
#define GG 8
#define HPAD 129   // s_hist row pitch (pad: rows are read down-column in poll phase)

static __device__ __forceinline__ float fexp2(float x) { return __builtin_amdgcn_exp2f(x); }
static __device__ __forceinline__ float frcp(float x)  { return __builtin_amdgcn_rcpf(x); }

// tanh for x >= 0: 1 - 2/(e^{2x}+1), e^{2x} = exp2(x * 2*log2(e))
static __device__ __forceinline__ float tanh_pos(float x) {
    float e = fexp2(x * 2.8853900817779268f);
    return 1.0f - 2.0f * frcp(e + 1.0f);
}

// plain store: write-through L1, lands (dirty) in the local XCD's L2
static __device__ __forceinline__ void gstore_plain(float* p, float v) {
    asm volatile("global_store_dword %0, %1, off" :: "v"(p), "v"(v) : "memory");
}
// sc0 load: bypass L1 (per-CU cache), served coherently by the XCD's L2
static __device__ __forceinline__ float gload_sc0(const float* p) {
    float v;
    asm volatile("global_load_dword %0, %1, off sc0\n\ts_waitcnt vmcnt(0)"
                 : "=v"(v) : "v"(p) : "memory");
    return v;
}

__global__ __launch_bounds__(512, 2)
void leaky_rnn_kernel(const float* __restrict__ x, const float* __restrict__ Rs,
                      const float* __restrict__ Wx2h, const float* __restrict__ Wh2h,
                      const float* __restrict__ bh2h, const float* __restrict__ Wh2o,
                      const float* __restrict__ bh2o, const float* __restrict__ Wattn,
                      const float* __restrict__ battn, const float* __restrict__ cplas,
                      float* __restrict__ out, float* __restrict__ hs,
                      unsigned* __restrict__ ctr)
{
    const int tid  = threadIdx.x;
    const int bid  = blockIdx.x;
    // XCD-local sibling mapping: dispatch round-robins XCDs (XCD = bid % 8),
    // so siblings of batch b are bids {b, b+32, ..., b+224} -- all == b (mod 8)
    // -> all 8 blocks of a batch share ONE XCD / ONE L2.
    const int b    = bid & 31;     // batch
    const int sub  = bid >> 5;     // 8 blocks per batch, 40 rows each
    const int w    = tid >> 6;     // wave 0..7
    const int lane = tid & 63;
    const int h0   = sub * 40;

    __shared__ float s_ea[GG * HH];      // masked relu(W_attn)
    __shared__ float s_out[HH];          // previous output for this b
    __shared__ float s_xm[II];           // modulated input
    __shared__ float s_logit[GG];
    __shared__ float s_hist[40 * HPAD];  // this block's 40 rows x 128 t (true values)
    __shared__ float s_hs[16 * HH];      // readout staging
    __shared__ int   s_mode;             // 1 = siblings verified same-XCD (L2-local comm)

    unsigned* slots = ctr + 1024;        // handshake slots at ws+4KB, 128B apart

    // publish own XCC_ID via the proven agent path (overlaps with init below)
    if (tid == 0) {
        unsigned xid;
        asm volatile("s_getreg_b32 %0, hwreg(HW_REG_XCC_ID)" : "=s"(xid));
        __hip_atomic_store(&slots[(b * 8 + sub) * 32], xid + 1u,
                           __ATOMIC_RELAXED, __HIP_MEMORY_SCOPE_AGENT);
    }

    // ---- one-time init ----
    for (int idx = tid; idx < GG * HH; idx += 512) {
        int h = idx % HH;
        float m = (h < 256) ? 1.f : (h == 256 ? -1.f : 0.f);  // mask_a (zc=63!)
        s_ea[idx] = fmaxf(Wattn[idx], 0.f) * m;
    }
    if (tid < HH) s_out[tid] = 0.f;   // output0 = relu(0)

    // plastic weights in registers: 5 rows/wave, lane owns cols {lane, lane+64,...}
    float wx[5][2], wh[5][5], st[5], bh[5];
    int hrow[5];
#pragma unroll
    for (int r = 0; r < 5; ++r) {
        int h = h0 + w * 5 + r;
        hrow[r] = h;
        bh[r] = bh2h[h];
        st[r] = 0.f;
#pragma unroll
        for (int c = 0; c < 2; ++c)
            wx[r][c] = fmaxf(Wx2h[h * II + lane + 64 * c], 0.f);   // wx0 = relu(W_x2h)
#pragma unroll
        for (int c = 0; c < 5; ++c) {
            int j = lane + 64 * c;
            float v = fmaxf(Wh2h[h * HH + j], 0.f);
            v = (c == 4) ? -v : v;            // sign_h: j>=256 -> -1
            wh[r][c] = (j == h) ? 0.f : v;    // zero diagonal (1-eye)
        }
    }
    float batt = battn[w];  // wave w handles attn group g = w
    float c0 = fabsf(cplas[0]), c1 = fabsf(cplas[1]), c2 = fabsf(cplas[2]);
    float c3 = fabsf(cplas[3]), c4 = fabsf(cplas[4]), c5 = fabsf(cplas[5]);

    const float AX  = (float)(0.02 / 0.1);   // 0.2
    const float AW  = (float)(0.02 / 0.2);   // 0.1
    const float OMX = 1.f - AX;
    const float OMW = 1.f - AW;
    const float L2E = 1.4426950408889634f;

    // gather siblings' XCC_IDs; fast mode iff all 8 match (deterministic:
    // every sibling reads the same 8 values -> identical decision)
    if (tid == 0) {
        unsigned xid;
        asm volatile("s_getreg_b32 %0, hwreg(HW_REG_XCC_ID)" : "=s"(xid));
        unsigned tag = xid + 1u;
        int ok = 1;
        for (int s2 = 0; s2 < 8; ++s2) {
            unsigned v = 0u; int g2 = 0;
            do {
                v = __hip_atomic_load(&slots[(b * 8 + s2) * 32],
                                      __ATOMIC_RELAXED, __HIP_MEMORY_SCOPE_AGENT);
            } while (v == 0u && ++g2 < 2000000);
            if (v != tag) ok = 0;
        }
        s_mode = ok;
    }

    __syncthreads();
    const bool fast = (s_mode != 0);

    // prefetch x, Rs for t=0
    float xv_next = (tid < II) ? x[b * II + tid] : 0.f;
    float Rv_next = Rs[b];

#pragma unroll 1
    for (int t = 0; t < TT; ++t) {
        float xv = xv_next;
        float Rv = Rv_next;
        float A  = AW * Rv;

        // ---- attention logits: g = w, reduce over H ----
        float lp = 0.f;
#pragma unroll
        for (int k = 0; k < 5; ++k) {
            int hh2 = lane + 64 * k;
            lp = fmaf(s_ea[w * HH + hh2], s_out[hh2], lp);
        }
#pragma unroll
        for (int m = 1; m < 64; m <<= 1) lp += __shfl_xor(lp, m, 64);
        if (lane == 0) s_logit[w] = lp + batt;
        __syncthreads();

        // ---- softmax + xm (threads 0..127 only) ----
        if (tid < II) {
            float lg[8];
#pragma unroll
            for (int g = 0; g < 8; ++g) lg[g] = s_logit[g];
            float mx = lg[0];
#pragma unroll
            for (int g = 1; g < 8; ++g) mx = fmaxf(mx, lg[g]);
            float se = 0.f, eg[8];
#pragma unroll
            for (int g = 0; g < 8; ++g) { eg[g] = fexp2((lg[g] - mx) * L2E); se += eg[g]; }
            s_xm[tid] = xv * eg[tid >> 4] * 8.f * frcp(se);  // * G / sum
        }
        __syncthreads();

        // ---- per-lane column values (reused for dot and update) ----
        float xmc0 = s_xm[lane], xmc1 = s_xm[lane + 64];
        float oc[5];
#pragma unroll
        for (int c = 0; c < 5; ++c) oc[c] = s_out[lane + 64 * c];

        // ---- 5 row-dot partials, then ILP-interleaved butterfly (same
        //      per-row reduction order as before -> bit-identical) ----
        float p[5];
#pragma unroll
        for (int r = 0; r < 5; ++r) {
            int h = hrow[r];
            float pp = fmaxf(wx[r][0], 0.f) * xmc0;
            pp = fmaf(fmaxf(wx[r][1], 0.f), xmc1, pp);
#pragma unroll
            for (int c = 0; c < 5; ++c) {
                float wv = fmaxf(wh[r][c], 0.f);
                float so = (c == 4) ? -oc[4] : oc[c];   // sign_h fold
                float term = wv * so;
                term = ((lane + 64 * c) == h) ? 0.f : term;  // exclude diagonal
                pp += term;
            }
            p[r] = pp;
        }
#pragma unroll
        for (int m = 1; m < 64; m <<= 1) {
#pragma unroll
            for (int r = 0; r < 5; ++r) p[r] += __shfl_xor(p[r], m, 64);
        }

        float no[5];
#pragma unroll
        for (int r = 0; r < 5; ++r) {
            float total = p[r] + bh[r];
            st[r] = fmaf(st[r], OMX, total * AX);
            no[r] = tanh_pos(fmaxf(st[r], 0.f));
        }

        // ---- batched publish: lanes 0..4 store 5 consecutive h in one
        //      coalesced cacheline. Biased (+2): poison/memset are <1.
        //      Dual publish in fast mode: agent first (LLC safety net),
        //      plain second (dirty line stays in the shared L2). ----
        {
            float pub = no[0];
            pub = (lane == 1) ? no[1] : pub;
            pub = (lane == 2) ? no[2] : pub;
            pub = (lane == 3) ? no[3] : pub;
            pub = (lane == 4) ? no[4] : pub;
            if (lane < 5) {
                float* dst = &hs[(t * BB + b) * HH + h0 + w * 5 + lane];
                __hip_atomic_store(dst, pub + 2.0f,
                                   __ATOMIC_RELAXED, __HIP_MEMORY_SCOPE_AGENT);
                if (fast) gstore_plain(dst, pub + 2.0f);
                s_hist[(w * 5 + lane) * HPAD + t] = pub;   // true value for final rewrite
            }
        }

        // ---- plastic weight update (regs only; overlaps store propagation) ----
        if (t < TT - 1) {
            float Ac0 = A * c0, Ac1 = A * c1, Ac2 = A * c2;
            float Ac3 = A * c3, Ac4 = A * c4, Ac5 = A * c5;
#pragma unroll
            for (int r = 0; r < 5; ++r) {
                float u  = fmaf(Ac2, no[r], Ac0);
                float v  = Ac1 * no[r];
                float pp = fmaf(Ac5, no[r], Ac3);
                float qq = Ac4 * no[r];
                wx[r][0] = fmaf(wx[r][0], OMW, fmaf(u, xmc0, v));
                wx[r][1] = fmaf(wx[r][1], OMW, fmaf(u, xmc1, v));
#pragma unroll
                for (int c = 0; c < 5; ++c)
                    wh[r][c] = fmaf(wh[r][c], OMW, fmaf(pp, oc[c], qq));
            }
        }

        // prefetch next x/R while peers' stores are in flight
        if (t + 1 < TT) {
            xv_next = (tid < II) ? x[((t + 1) * BB + b) * II + tid] : 0.f;
            Rv_next = Rs[(t + 1) * BB + b];
        }

        __syncthreads();   // all reads of s_out / s_hist-write visibility before overwrite

        // ---- gather next-step output vector by POLLING THE DATA.
        //      fast: sc0 loads served by the shared XCD L2 (~200cy);
        //      bounded fallback to the agent/LLC path keeps correctness
        //      under any mapping/cache-semantics surprise. ----
        if (t < TT - 1 && tid < HH) {
            float v = 0.f;
            if (tid >= h0 && tid < h0 + 40) {
                v = s_hist[(tid - h0) * HPAD + t];   // own rows: LDS, already true value
            } else {
                const float* p2 = &hs[(t * BB + b) * HH + tid];
                if (fast) {
                    int guard = 0;
                    do {
                        v = gload_sc0(p2);
                    } while (v < 1.0f && ++guard < 3000);
                }
                if (v < 1.0f) {                       // slow path / safety net
                    int guard = 0;
                    do {
                        v = __hip_atomic_load(p2, __ATOMIC_RELAXED,
                                              __HIP_MEMORY_SCOPE_AGENT);
                    } while (v < 1.0f && ++guard < 2000000);
                }
                v -= 2.0f;
            }
            s_out[tid] = v;
        }
        __syncthreads();
    }

    // ======== final phase ========
    // Barrier A among the 8 sibling blocks: everyone's t-loop done, all hs published.
    if (tid == 0) {
        __hip_atomic_fetch_add(&ctr[b * 32], 1u, __ATOMIC_RELAXED, __HIP_MEMORY_SCOPE_AGENT);
        int guard = 0;
        while (__hip_atomic_load(&ctr[b * 32], __ATOMIC_RELAXED, __HIP_MEMORY_SCOPE_AGENT) < 8u) {
            if (++guard > 2000000) break;
            __builtin_amdgcn_s_sleep(1);
        }
    }
    __syncthreads();

    // readout staging: load biased hs, subtract bias (fast: L2-local sc0 loads)
    for (int idx = tid; idx < 16 * HH; idx += 512) {
        int tl = idx / HH, h = idx % HH;
        int t_g = sub * 16 + tl;
        const float* p2 = &hs[(t_g * BB + b) * HH + h];
        float v = fast ? gload_sc0(p2)
                       : __hip_atomic_load(p2, __ATOMIC_RELAXED, __HIP_MEMORY_SCOPE_AGENT);
        s_hs[idx] = v - 2.0f;
    }
    __syncthreads();
    {
        int t_loc = tid >> 5;          // 0..15
        int o     = tid & 31;
        int t_g   = sub * 16 + t_loc;
        const float* hp = &s_hs[t_loc * HH];
        float acc = bh2o[o];
#pragma unroll 4
        for (int h = 0; h < 257; ++h) {          // mask_o zero for h>256
            float m = (h == 256) ? -1.f : 1.f;   // h==256: sign -1, exist 1 (zc=63)
            acc = fmaf(fmaxf(Wh2o[o * HH + h], 0.f) * m, hp[h], acc);
        }
        float sg = frcp(1.f + fexp2(-acc * L2E));
        out[(t_g * BB + b) * OO + o] = sg;
    }

    // Barrier B: all siblings finished READING biased hs -> safe to rewrite
    __syncthreads();
    if (tid == 0) {
        __hip_atomic_fetch_add(&ctr[b * 32], 1u, __ATOMIC_RELAXED, __HIP_MEMORY_SCOPE_AGENT);
        int guard = 0;
        while (__hip_atomic_load(&ctr[b * 32], __ATOMIC_RELAXED, __HIP_MEMORY_SCOPE_AGENT) < 16u) {
            if (++guard > 2000000) break;
            __builtin_amdgcn_s_sleep(1);
        }
    }
    __syncthreads();

    // rewrite own rows of hs with TRUE values.
    // fast: plain stores merge in the single shared L2 (kernel-end release
    // writes back); slow: word-granular agent stores (no cross-XCD
    // partial-dirty-line merge concerns).
    for (int idx = tid; idx < 40 * TT; idx += 512) {
        int row = idx >> 7;            // idx / 128
        int t   = idx & 127;
        float* dst = &hs[(t * BB + b) * HH + h0 + row];
        float tv = s_hist[row * HPAD + t];
        if (fast) gstore_plain(dst, tv);
        else __hip_atomic_store(dst, tv, __ATOMIC_RELAXED, __HIP_MEMORY_SCOPE_AGENT);
    }
}

extern "C" void kernel_launch(void* const* d_in, const int* in_sizes, int n_in,
                              void* d_out, int out_size, void* d_ws, size_t ws_size,
                              hipStream_t stream) {
    const float* x     = (const float*)d_in[0];
    const float* Rs    = (const float*)d_in[1];
    const float* Wx2h  = (const float*)d_in[2];
    const float* Wh2h  = (const float*)d_in[3];
    const float* bh2h  = (const float*)d_in[4];
    const float* Wh2o  = (const float*)d_in[5];
    const float* bh2o  = (const float*)d_in[6];
    const float* Wattn = (const float*)d_in[7];
    const float* battn = (const float*)d_in[8];
    const float* cplas = (const float*)d_in[9];
    float* out = (float*)d_out;
    float* hs  = out + TT * BB * OO;
    unsigned* ctr = (unsigned*)d_ws;   // [0,4KB): barrier ctrs; [4KB,36KB): XCD handshake

    hipMemsetAsync(d_ws, 0, 36864, stream);
    hipLaunchKernelGGL(leaky_rnn_kernel, dim3(256), dim3(512), 0, stream,
                       x, Rs, Wx2h, Wh2h, bh2h, Wh2o, bh2o, Wattn, battn, cplas,
                       out, hs, ctr);
}

// Round 2
// 476.742 us; speedup vs baseline: 55.0664x; 55.0664x over previous
//
#include <hip/hip_runtime.h>

#define TT 128
#define BB 32
#define II 128
#define HH 320
#define OO 32
#define GG 8
#define HPAD 129   // s_hist row pitch (pad: rows are read down-column in final rewrite)

static __device__ __forceinline__ float fexp2(float x) { return __builtin_amdgcn_exp2f(x); }
static __device__ __forceinline__ float frcp(float x)  { return __builtin_amdgcn_rcpf(x); }

// tanh for x >= 0: 1 - 2/(e^{2x}+1), e^{2x} = exp2(x * 2*log2(e))
static __device__ __forceinline__ float tanh_pos(float x) {
    float e = fexp2(x * 2.8853900817779268f);
    return 1.0f - 2.0f * frcp(e + 1.0f);
}

__global__ __launch_bounds__(512, 2)
void leaky_rnn_kernel(const float* __restrict__ x, const float* __restrict__ Rs,
                      const float* __restrict__ Wx2h, const float* __restrict__ Wh2h,
                      const float* __restrict__ bh2h, const float* __restrict__ Wh2o,
                      const float* __restrict__ bh2o, const float* __restrict__ Wattn,
                      const float* __restrict__ battn, const float* __restrict__ cplas,
                      float* __restrict__ out, float* __restrict__ hs,
                      unsigned* __restrict__ ctr)
{
    const int tid  = threadIdx.x;
    const int bid  = blockIdx.x;
    const int b    = bid >> 3;     // batch  (round-0 proven mapping)
    const int sub  = bid & 7;      // 8 blocks per batch, 40 rows each
    const int w    = tid >> 6;     // wave 0..7
    const int lane = tid & 63;
    const int h0   = sub * 40;

    __shared__ float s_ea[GG * HH];      // masked relu(W_attn)
    __shared__ float s_out[2][HH];       // double-buffered prev-output (by t parity)
    __shared__ float s_logit[GG];
    __shared__ float s_hist[40 * HPAD];  // this block's 40 rows x 128 t (true values)
    __shared__ float s_hs[16 * HH];      // readout staging

    // ---- one-time init ----
    for (int idx = tid; idx < GG * HH; idx += 512) {
        int h = idx % HH;
        float m = (h < 256) ? 1.f : (h == 256 ? -1.f : 0.f);  // mask_a (zc=63!)
        s_ea[idx] = fmaxf(Wattn[idx], 0.f) * m;
    }
    if (tid < HH) { s_out[0][tid] = 0.f; s_out[1][tid] = 0.f; }  // output0 = relu(0)

    // plastic weights in registers: 5 rows/wave, lane owns cols {lane, lane+64,...}
    float wx[5][2], wh[5][5], st[5], bh[5];
    int hrow[5];
#pragma unroll
    for (int r = 0; r < 5; ++r) {
        int h = h0 + w * 5 + r;
        hrow[r] = h;
        bh[r] = bh2h[h];
        st[r] = 0.f;
#pragma unroll
        for (int c = 0; c < 2; ++c)
            wx[r][c] = fmaxf(Wx2h[h * II + lane + 64 * c], 0.f);   // wx0 = relu(W_x2h)
#pragma unroll
        for (int c = 0; c < 5; ++c) {
            int j = lane + 64 * c;
            float v = fmaxf(Wh2h[h * HH + j], 0.f);
            v = (c == 4) ? -v : v;            // sign_h: j>=256 -> -1
            wh[r][c] = (j == h) ? 0.f : v;    // zero diagonal (1-eye)
        }
    }
    float batt = battn[w];  // wave w handles attn group g = w
    float c0 = fabsf(cplas[0]), c1 = fabsf(cplas[1]), c2 = fabsf(cplas[2]);
    float c3 = fabsf(cplas[3]), c4 = fabsf(cplas[4]), c5 = fabsf(cplas[5]);

    const float AX  = (float)(0.02 / 0.1);   // 0.2
    const float AW  = (float)(0.02 / 0.2);   // 0.1
    const float OMX = 1.f - AX;
    const float OMW = 1.f - AW;
    const float L2E = 1.4426950408889634f;

    __syncthreads();

    // prefetch x (both halves, per-thread regs) and Rs for t=0
    float xv0n = x[b * II + lane];
    float xv1n = x[b * II + lane + 64];
    float Rvn  = Rs[b];

#pragma unroll 1
    for (int t = 0; t < TT; ++t) {
        const float* so_cur = s_out[t & 1];
        float*       so_nxt = s_out[(t + 1) & 1];
        float xv0 = xv0n, xv1 = xv1n;
        float A   = AW * Rvn;

        // ---- attention logits: g = w, reduce over H ----
        float lp = 0.f;
#pragma unroll
        for (int k = 0; k < 5; ++k) {
            int hh2 = lane + 64 * k;
            lp = fmaf(s_ea[w * HH + hh2], so_cur[hh2], lp);
        }
#pragma unroll
        for (int m = 1; m < 64; m <<= 1) lp += __shfl_xor(lp, m, 64);
        if (lane == 0) s_logit[w] = lp + batt;
        __syncthreads();                                   // B1: s_logit visible

        // ---- redundant per-thread softmax (replaces staged s_xm + barrier) ----
        float lg[8];
#pragma unroll
        for (int g = 0; g < 8; ++g) lg[g] = s_logit[g];
        float mx = lg[0];
#pragma unroll
        for (int g = 1; g < 8; ++g) mx = fmaxf(mx, lg[g]);
        float se = 0.f, eg[8];
#pragma unroll
        for (int g = 0; g < 8; ++g) { eg[g] = fexp2((lg[g] - mx) * L2E); se += eg[g]; }
        float rinv = frcp(se);
        // same op order as before: ((xv*eg)*8)*rinv -> bit-identical
        float xmc0 = xv0 * eg[lane >> 4] * 8.f * rinv;
        float xmc1 = xv1 * eg[(lane >> 4) + 4] * 8.f * rinv;

        float oc[5];
#pragma unroll
        for (int c = 0; c < 5; ++c) oc[c] = so_cur[lane + 64 * c];

        // ---- 5 row-dot partials, ILP-interleaved butterfly ----
        float p[5];
#pragma unroll
        for (int r = 0; r < 5; ++r) {
            int h = hrow[r];
            float pp = fmaxf(wx[r][0], 0.f) * xmc0;
            pp = fmaf(fmaxf(wx[r][1], 0.f), xmc1, pp);
#pragma unroll
            for (int c = 0; c < 5; ++c) {
                float wv = fmaxf(wh[r][c], 0.f);
                float so = (c == 4) ? -oc[4] : oc[c];        // sign_h fold
                float term = wv * so;
                term = ((lane + 64 * c) == h) ? 0.f : term;  // exclude diagonal
                pp += term;
            }
            p[r] = pp;
        }
#pragma unroll
        for (int m = 1; m < 64; m <<= 1) {
#pragma unroll
            for (int r = 0; r < 5; ++r) p[r] += __shfl_xor(p[r], m, 64);
        }

        float no[5];
#pragma unroll
        for (int r = 0; r < 5; ++r) {
            float total = p[r] + bh[r];
            st[r] = fmaf(st[r], OMX, total * AX);
            no[r] = tanh_pos(fmaxf(st[r], 0.f));
        }

        // ---- batched publish: lanes 0..4 store 5 consecutive h (one line).
        //      Biased (+2): poison 0xAA.. and memset-0 are < 1. ----
        {
            float pub = no[0];
            pub = (lane == 1) ? no[1] : pub;
            pub = (lane == 2) ? no[2] : pub;
            pub = (lane == 3) ? no[3] : pub;
            pub = (lane == 4) ? no[4] : pub;
            if (lane < 5) {
                __hip_atomic_store(&hs[(t * BB + b) * HH + h0 + w * 5 + lane], pub + 2.0f,
                                   __ATOMIC_RELAXED, __HIP_MEMORY_SCOPE_AGENT);
                s_hist[(w * 5 + lane) * HPAD + t] = pub;   // true value for final rewrite
            }
        }

        // ---- plastic weight update (regs only; overlaps store propagation) ----
        if (t < TT - 1) {
            float Ac0 = A * c0, Ac1 = A * c1, Ac2 = A * c2;
            float Ac3 = A * c3, Ac4 = A * c4, Ac5 = A * c5;
#pragma unroll
            for (int r = 0; r < 5; ++r) {
                float u  = fmaf(Ac2, no[r], Ac0);
                float v  = Ac1 * no[r];
                float pp = fmaf(Ac5, no[r], Ac3);
                float qq = Ac4 * no[r];
                wx[r][0] = fmaf(wx[r][0], OMW, fmaf(u, xmc0, v));
                wx[r][1] = fmaf(wx[r][1], OMW, fmaf(u, xmc1, v));
#pragma unroll
                for (int c = 0; c < 5; ++c)
                    wh[r][c] = fmaf(wh[r][c], OMW, fmaf(pp, oc[c], qq));
            }
        }

        // prefetch next x/R while publish stores are in flight
        if (t + 1 < TT) {
            xv0n = x[((t + 1) * BB + b) * II + lane];
            xv1n = x[((t + 1) * BB + b) * II + lane + 64];
            Rvn  = Rs[(t + 1) * BB + b];
        }

        // ---- gather next-step output into the OTHER buffer (no WAR barrier
        //      needed: nobody reads so_nxt during step t). Poll the DATA
        //      (data-is-flag, single RTT). Own rows' stores are oldest in
        //      flight -> visible first. ----
        if (t < TT - 1 && tid < HH) {
            const float* p2 = &hs[(t * BB + b) * HH + tid];
            float v; int guard = 0;
            do {
                v = __hip_atomic_load(p2, __ATOMIC_RELAXED, __HIP_MEMORY_SCOPE_AGENT);
            } while (v < 1.0f && ++guard < 2000000);   // failsafe: never hang
            so_nxt[tid] = v - 2.0f;
        }
        __syncthreads();                                   // B2: so_nxt sealed
    }

    // ======== final phase ========
    // Barrier A among the 8 sibling blocks: everyone's t-loop done, all hs published.
    if (tid == 0) {
        __hip_atomic_fetch_add(&ctr[b * 32], 1u, __ATOMIC_RELAXED, __HIP_MEMORY_SCOPE_AGENT);
        int guard = 0;
        while (__hip_atomic_load(&ctr[b * 32], __ATOMIC_RELAXED, __HIP_MEMORY_SCOPE_AGENT) < 8u) {
            if (++guard > 2000000) break;
            __builtin_amdgcn_s_sleep(1);
        }
    }
    __syncthreads();

    // readout staging: load biased hs, subtract bias
    for (int idx = tid; idx < 16 * HH; idx += 512) {
        int tl = idx / HH, h = idx % HH;
        int t_g = sub * 16 + tl;
        s_hs[idx] = __hip_atomic_load(&hs[(t_g * BB + b) * HH + h],
                                      __ATOMIC_RELAXED, __HIP_MEMORY_SCOPE_AGENT) - 2.0f;
    }
    __syncthreads();
    {
        int t_loc = tid >> 5;          // 0..15
        int o     = tid & 31;
        int t_g   = sub * 16 + t_loc;
        const float* hp = &s_hs[t_loc * HH];
        float acc = bh2o[o];
#pragma unroll 4
        for (int h = 0; h < 257; ++h) {          // mask_o zero for h>256
            float m = (h == 256) ? -1.f : 1.f;   // h==256: sign -1, exist 1 (zc=63)
            acc = fmaf(fmaxf(Wh2o[o * HH + h], 0.f) * m, hp[h], acc);
        }
        float sg = frcp(1.f + fexp2(-acc * L2E));
        out[(t_g * BB + b) * OO + o] = sg;
    }

    // Barrier B: all siblings finished READING biased hs -> safe to rewrite
    __syncthreads();
    if (tid == 0) {
        __hip_atomic_fetch_add(&ctr[b * 32], 1u, __ATOMIC_RELAXED, __HIP_MEMORY_SCOPE_AGENT);
        int guard = 0;
        while (__hip_atomic_load(&ctr[b * 32], __ATOMIC_RELAXED, __HIP_MEMORY_SCOPE_AGENT) < 16u) {
            if (++guard > 2000000) break;
            __builtin_amdgcn_s_sleep(1);
        }
    }
    __syncthreads();

    // rewrite own rows of hs with TRUE values (word-granular agent stores:
    // no cross-XCD partial-dirty-line merge concerns)
    for (int idx = tid; idx < 40 * TT; idx += 512) {
        int row = idx >> 7;            // idx / 128
        int t   = idx & 127;
        __hip_atomic_store(&hs[(t * BB + b) * HH + h0 + row], s_hist[row * HPAD + t],
                           __ATOMIC_RELAXED, __HIP_MEMORY_SCOPE_AGENT);
    }
}

extern "C" void kernel_launch(void* const* d_in, const int* in_sizes, int n_in,
                              void* d_out, int out_size, void* d_ws, size_t ws_size,
                              hipStream_t stream) {
    const float* x     = (const float*)d_in[0];
    const float* Rs    = (const float*)d_in[1];
    const float* Wx2h  = (const float*)d_in[2];
    const float* Wh2h  = (const float*)d_in[3];
    const float* bh2h  = (const float*)d_in[4];
    const float* Wh2o  = (const float*)d_in[5];
    const float* bh2o  = (const float*)d_in[6];
    const float* Wattn = (const float*)d_in[7];
    const float* battn = (const float*)d_in[8];
    const float* cplas = (const float*)d_in[9];
    float* out = (float*)d_out;
    float* hs  = out + TT * BB * OO;
    unsigned* ctr = (unsigned*)d_ws;   // 32 counters, 128B apart

    hipMemsetAsync(d_ws, 0, 32 * 32 * sizeof(unsigned), stream);
    hipLaunchKernelGGL(leaky_rnn_kernel, dim3(256), dim3(512), 0, stream,
                       x, Rs, Wx2h, Wh2h, bh2h, Wh2o, bh2o, Wattn, battn, cplas,
                       out, hs, ctr);
}